// Round 3
// baseline (834.777 us; speedup 1.0000x reference)
//
#include <hip/hip_runtime.h>
#include <stdint.h>

// ---------------------------------------------------------------------------
// PerceiverAttention fused pipeline (MI355X / gfx950), bf16 MFMA compute.
// b=8, f=8192, n=64, d=1024, heads=8, dim_head=64, inner=512.
// Round 3: scan kernel removed (atomic slot assignment in prep; softmax is
// permutation-invariant over kv slots so compaction order is arbitrary);
// LN + weight transposes merged into one prep kernel; latent K/V/Q
// projections fused into one GEMM vs [Wk|Wv|Wq]^T (N=1536).
// ---------------------------------------------------------------------------

#define KVPAD 8448
#define NCHUNK 33

typedef __attribute__((ext_vector_type(8))) short short8;
typedef __attribute__((ext_vector_type(4))) float f32x4;

typedef __attribute__((address_space(1))) void gvoid;
typedef __attribute__((address_space(3))) void lvoid;

__device__ __forceinline__ unsigned short f2bf(float f) {
    union { float f; uint32_t u; } v; v.f = f;
    uint32_t u = v.u;
    u += 0x7fffu + ((u >> 16) & 1u);   // RNE
    return (unsigned short)(u >> 16);
}

__device__ __forceinline__ void mfma16(f32x4& c, short8 a, short8 b) {
    asm volatile("v_mfma_f32_16x16x32_bf16 %0, %1, %2, %0"
                 : "+v"(c) : "v"(a), "v"(b));
}

__device__ __forceinline__ void gl2lds16(const void* g, void* l) {
    __builtin_amdgcn_global_load_lds((gvoid*)g, (lvoid*)l, 16, 0, 0);
}

// ---------------------------------------------------------------------------
// prep: blocks [0,16512) = LayerNorm (x compacted via atomic slot + latents),
// blocks [16512,17024) = the 4 weight transposes (fp32 -> bf16, R x C -> C x R).
// Compaction order is arbitrary (softmax permutation-invariant) -> atomicAdd.
// ---------------------------------------------------------------------------
__global__ __launch_bounds__(256) void prep_kernel(
    const float* __restrict__ X, const float* __restrict__ latents,
    const int* __restrict__ mask,
    const float* __restrict__ gm, const float* __restrict__ bm,
    const float* __restrict__ gl, const float* __restrict__ bl,
    const float* __restrict__ Wk, const float* __restrict__ Wv,
    const float* __restrict__ Wq, const float* __restrict__ Wout,
    unsigned short* __restrict__ x_ln, unsigned short* __restrict__ lat_ln,
    unsigned short* __restrict__ WkvqT, unsigned short* __restrict__ WoutT,
    int* __restrict__ cnt)
{
    __shared__ float t[64][65];
    int blk = blockIdx.x;
    if (blk >= 16512) {
        // ---- weight transpose part ----
        int tt = blk - 16512;              // 0..511
        int z = tt >> 7, u = tt & 127;
        const float* S; unsigned short* D; int R, C, bx, by;
        if (z == 0)      { S = Wk;   D = WkvqT;                       R = 1024; C = 512;  by = u >> 3; bx = u & 7; }
        else if (z == 1) { S = Wv;   D = WkvqT + (size_t)512 * 1024;  R = 1024; C = 512;  by = u >> 3; bx = u & 7; }
        else if (z == 2) { S = Wq;   D = WkvqT + (size_t)1024 * 1024; R = 1024; C = 512;  by = u >> 3; bx = u & 7; }
        else             { S = Wout; D = WoutT;                       R = 512;  C = 1024; by = u >> 4; bx = u & 15; }
        int r0 = by * 64, c0 = bx * 64;
#pragma unroll
        for (int i = 0; i < 16; i++) {
            int o = i * 256 + threadIdx.x;
            int rr = o >> 6, cc = o & 63;
            t[rr][cc] = S[(size_t)(r0 + rr) * C + c0 + cc];
        }
        __syncthreads();
#pragma unroll
        for (int i = 0; i < 16; i++) {
            int o = i * 256 + threadIdx.x;
            int cl = o >> 6, rl = o & 63;
            D[(size_t)(c0 + cl) * R + r0 + rl] = f2bf(t[rl][cl]);
        }
        return;
    }
    // ---- LayerNorm part: one wave per row ----
    int lane = threadIdx.x & 63;
    int row = blk * 4 + (threadIdx.x >> 6);
    const float *src, *g, *bet;
    unsigned short* dst;
    if (row < 65536) {
        if (mask[row] != 0) return;                 // padded: skip entirely
        int b = row >> 13;
        int slot;
        if (lane == 0) slot = atomicAdd(&cnt[b], 1);
        slot = __shfl(slot, 0);
        src = X + (size_t)row * 1024;
        dst = x_ln + ((size_t)b * 8192 + slot) * 1024;
        g = gm; bet = bm;
    } else {
        int r = row - 65536;                        // 0..511
        src = latents + (size_t)r * 1024;
        dst = lat_ln + (size_t)r * 1024;
        g = gl; bet = bl;
    }
    const float4* xr = (const float4*)src;
    float4 v[4];
    float s = 0.f, s2 = 0.f;
#pragma unroll
    for (int i = 0; i < 4; i++) {
        v[i] = xr[i * 64 + lane];
        s  += v[i].x + v[i].y + v[i].z + v[i].w;
        s2 += v[i].x*v[i].x + v[i].y*v[i].y + v[i].z*v[i].z + v[i].w*v[i].w;
    }
#pragma unroll
    for (int off = 1; off < 64; off <<= 1) {
        s += __shfl_xor(s, off);
        s2 += __shfl_xor(s2, off);
    }
    float mean = s * (1.0f / 1024.0f);
    float var  = s2 * (1.0f / 1024.0f) - mean * mean;
    float rs = rsqrtf(var + 1e-5f);
    ushort4* yr = (ushort4*)dst;
    const float4* gp = (const float4*)g;
    const float4* bp = (const float4*)bet;
#pragma unroll
    for (int i = 0; i < 4; i++) {
        int c4 = i * 64 + lane;
        float4 gg = gp[c4], bb = bp[c4];
        ushort4 o;
        o.x = f2bf((v[i].x - mean) * rs * gg.x + bb.x);
        o.y = f2bf((v[i].y - mean) * rs * gg.y + bb.y);
        o.z = f2bf((v[i].z - mean) * rs * gg.z + bb.z);
        o.w = f2bf((v[i].w - mean) * rs * gg.w + bb.w);
        yr[c4] = o;
    }
}

// ---------------------------------------------------------------------------
// Generic bf16 GEMM: C[M][N] = A[M][Kd] @ BT[N][Kd]^T, 128x128 tile, BK=64.
// m97 structure + 8x8 tile swizzle (only for the 8x512 grid) + per-batch
// early exit on cnt. Store modes per output column:
//   col >= nq     : Q store,  Qb[(bq*64+rl+r)*512 + col-nq] * qscale (bf16)
//   col <  nsplit : row-major (bf16 Ck or fp32 Cf), row -> bq*Sstride+Ofs+rl
//   else          : transposed to CvT[(bq*512 + col-nsplit)*KVPAD + Ofs+rl]
// ---------------------------------------------------------------------------
__global__ __launch_bounds__(256) void gemm_bf16(
    const unsigned short* __restrict__ A, const unsigned short* __restrict__ BT,
    int Kd,
    unsigned short* __restrict__ Ck, float* __restrict__ Cf,
    unsigned short* __restrict__ CvT, unsigned short* __restrict__ Qb,
    int nsplit, int nq, int ldc, int P, int Sstride, int Ofs,
    float scale_const, float qscale, const float* __restrict__ scale_ptr,
    const int* __restrict__ cnt)
{
    __shared__ unsigned short a_lds[128 * 64];
    __shared__ unsigned short b_lds[128 * 64];
    int bx = blockIdx.x, by = blockIdx.y;
    if (gridDim.x == 8 && gridDim.y >= 8) {
        // 8x8 tile swizzle: 8 column-blocks sharing an A row-tile run in the
        // same 64-block window -> A re-reads hit L2/L3.
        int lid = by * 8 + bx;
        bx = lid & 7;
        by = (lid >> 6) * 8 + ((lid >> 3) & 7);
    }
    size_t rowbase = (size_t)by * 128;
    size_t colbase = (size_t)bx * 128;
    if (cnt) {  // compacted A: skip row-blocks past this batch's valid count
        int bq = (int)rowbase / P, rl = (int)rowbase - bq * P;
        if (rl >= cnt[bq]) return;
    }
    int tid = threadIdx.x;
    int lane = tid & 63;
    int wave = tid >> 6;
    int wrow = (wave >> 1) * 64, wcol = (wave & 1) * 64;
    int qd = lane >> 4, cc = lane & 15;

    f32x4 acc[4][4];
#pragma unroll
    for (int mt = 0; mt < 4; mt++)
#pragma unroll
        for (int nt = 0; nt < 4; nt++)
            acc[mt][nt] = (f32x4){0.f, 0.f, 0.f, 0.f};

    int kiters = Kd >> 6;
    for (int kt = 0; kt < kiters; kt++) {
        int k0 = kt << 6;
#pragma unroll
        for (int i = 0; i < 4; i++) {
            int s = i * 256 + tid;
            int m = s >> 3, kc = s & 7;
            int kg = kc ^ (m & 7);
            gl2lds16(A + (rowbase + m) * (size_t)Kd + (k0 + kg * 8), &a_lds[s * 8]);
        }
#pragma unroll
        for (int i = 0; i < 4; i++) {
            int s = i * 256 + tid;
            int m = s >> 3, kc = s & 7;
            int kg = kc ^ (m & 7);
            gl2lds16(BT + (colbase + m) * (size_t)Kd + (k0 + kg * 8), &b_lds[s * 8]);
        }
        __syncthreads();
#pragma unroll
        for (int ks = 0; ks < 2; ks++) {
            short8 af[4], bfr[4];
            int cg = ks * 4 + qd;
#pragma unroll
            for (int mt = 0; mt < 4; mt++) {
                int m = wrow + mt * 16 + cc;
                af[mt] = *(const short8*)&a_lds[(m * 8 + (cg ^ (m & 7))) * 8];
            }
#pragma unroll
            for (int nt = 0; nt < 4; nt++) {
                int n = wcol + nt * 16 + cc;
                bfr[nt] = *(const short8*)&b_lds[(n * 8 + (cg ^ (n & 7))) * 8];
            }
#pragma unroll
            for (int mt = 0; mt < 4; mt++)
#pragma unroll
                for (int nt = 0; nt < 4; nt++)
                    mfma16(acc[mt][nt], af[mt], bfr[nt]);
        }
        __syncthreads();
    }

    float sc = scale_const;
    if (scale_ptr) sc *= *scale_ptr;
#pragma unroll
    for (int mt = 0; mt < 4; mt++) {
        int g0 = (int)rowbase + wrow + mt * 16 + qd * 4;   // 4 consecutive rows
        int bq = g0 / P, rl = g0 - bq * P;
#pragma unroll
        for (int nt = 0; nt < 4; nt++) {
            int col = (int)colbase + wcol + nt * 16 + cc;
            if (col >= nq) {
#pragma unroll
                for (int r = 0; r < 4; r++)
                    Qb[(size_t)(bq * 64 + rl + r) * 512 + (col - nq)] =
                        f2bf(acc[mt][nt][r] * qscale);
            } else if (col < nsplit) {
                int idx0 = bq * Sstride + Ofs + rl;
                if (Cf) {
#pragma unroll
                    for (int r = 0; r < 4; r++)
                        Cf[(size_t)(idx0 + r) * ldc + col] = acc[mt][nt][r] * sc;
                } else {
#pragma unroll
                    for (int r = 0; r < 4; r++)
                        Ck[(size_t)(idx0 + r) * ldc + col] = f2bf(acc[mt][nt][r] * sc);
                }
            } else {
                ushort4 pk;
                pk.x = f2bf(acc[mt][nt][0] * sc);
                pk.y = f2bf(acc[mt][nt][1] * sc);
                pk.z = f2bf(acc[mt][nt][2] * sc);
                pk.w = f2bf(acc[mt][nt][3] * sc);
                *(ushort4*)&CvT[((size_t)bq * 512 + (col - nsplit)) * KVPAD + Ofs + rl] = pk;
            }
        }
    }
}

// ---------------------------------------------------------------------------
// Attention, split-kv over compacted layout. Grid (chunk=33, h=8, b=8).
// kv slots: [0..64) latents, [64..64+cnt[b]) features; len = 64+cnt[b].
// Blocks with kv0 >= len exit (their partials are never read by combine).
// ---------------------------------------------------------------------------
__global__ __launch_bounds__(256) void attn_kernel(
    const unsigned short* __restrict__ Kbuf,  // [8][8448][512]
    const unsigned short* __restrict__ Vt,    // [8][512][8448]
    const unsigned short* __restrict__ Qbuf,  // [8][64][512]
    const int* __restrict__ cnt,              // [8]
    float* __restrict__ Opart,                // [2112][64][64]
    float* __restrict__ Mpart,                // [2112][64]
    float* __restrict__ Lpart)                // [2112][64]
{
    __shared__ unsigned short P_lds[64 * 264];
    __shared__ float red_max[4][64];
    __shared__ float red_sum[4][64];
    __shared__ float mrow[64];

    int chunk = blockIdx.x, h = blockIdx.y, b = blockIdx.z;
    int len = 64 + cnt[b];
    int kv0 = chunk * 256;
    if (kv0 >= len) return;

    int tid = threadIdx.x, lane = tid & 63, w = tid >> 6;
    int qd = lane >> 4, cc = lane & 15;
    int pidx = (b * 8 + h) * NCHUNK + chunk;
    int kvw = kv0 + w * 64;

    short8 qf[4][2];
    const unsigned short* Qb = Qbuf + ((size_t)b * 64) * 512 + h * 64;
#pragma unroll
    for (int mt = 0; mt < 4; mt++)
#pragma unroll
        for (int ks = 0; ks < 2; ks++)
            qf[mt][ks] = *(const short8*)&Qb[(size_t)(mt * 16 + cc) * 512 + ks * 32 + qd * 8];

    f32x4 acc[4][4];
#pragma unroll
    for (int mt = 0; mt < 4; mt++)
#pragma unroll
        for (int nt = 0; nt < 4; nt++)
            acc[mt][nt] = (f32x4){0.f, 0.f, 0.f, 0.f};

    const unsigned short* Kb = Kbuf + (size_t)b * KVPAD * 512 + h * 64;
#pragma unroll
    for (int nt = 0; nt < 4; nt++) {
        int kvr = kvw + nt * 16 + cc;
#pragma unroll
        for (int ks = 0; ks < 2; ks++) {
            short8 kf = *(const short8*)&Kb[(size_t)kvr * 512 + ks * 32 + qd * 8];
#pragma unroll
            for (int mt = 0; mt < 4; mt++)
                mfma16(acc[mt][nt], qf[mt][ks], kf);
        }
    }
    // compacted: only slots >= len are invalid
#pragma unroll
    for (int nt = 0; nt < 4; nt++) {
        int kv = kvw + nt * 16 + cc;
        if (kv >= len) {
#pragma unroll
            for (int mt = 0; mt < 4; mt++)
#pragma unroll
                for (int r = 0; r < 4; r++) acc[mt][nt][r] = -1e30f;
        }
    }
    float vmax[4][4];
#pragma unroll
    for (int mt = 0; mt < 4; mt++)
#pragma unroll
        for (int r = 0; r < 4; r++)
            vmax[mt][r] = fmaxf(fmaxf(acc[mt][0][r], acc[mt][1][r]),
                                fmaxf(acc[mt][2][r], acc[mt][3][r]));
#pragma unroll
    for (int off = 1; off < 16; off <<= 1)
#pragma unroll
        for (int mt = 0; mt < 4; mt++)
#pragma unroll
            for (int r = 0; r < 4; r++)
                vmax[mt][r] = fmaxf(vmax[mt][r], __shfl_xor(vmax[mt][r], off));
    if (cc == 0) {
#pragma unroll
        for (int mt = 0; mt < 4; mt++)
#pragma unroll
            for (int r = 0; r < 4; r++)
                red_max[w][mt * 16 + qd * 4 + r] = vmax[mt][r];
    }
    __syncthreads();
    if (tid < 64)
        mrow[tid] = fmaxf(fmaxf(red_max[0][tid], red_max[1][tid]),
                          fmaxf(red_max[2][tid], red_max[3][tid]));
    __syncthreads();

    float vsum[4][4];
#pragma unroll
    for (int mt = 0; mt < 4; mt++)
#pragma unroll
        for (int r = 0; r < 4; r++) {
            int row = mt * 16 + qd * 4 + r;
            float m = mrow[row];
            float ssum = 0.f;
#pragma unroll
            for (int nt = 0; nt < 4; nt++) {
                float p = __expf(acc[mt][nt][r] - m);
                ssum += p;
                P_lds[row * 264 + w * 64 + nt * 16 + cc] = f2bf(p);
            }
            vsum[mt][r] = ssum;
        }
#pragma unroll
    for (int off = 1; off < 16; off <<= 1)
#pragma unroll
        for (int mt = 0; mt < 4; mt++)
#pragma unroll
            for (int r = 0; r < 4; r++)
                vsum[mt][r] += __shfl_xor(vsum[mt][r], off);
    if (cc == 0) {
#pragma unroll
        for (int mt = 0; mt < 4; mt++)
#pragma unroll
            for (int r = 0; r < 4; r++)
                red_sum[w][mt * 16 + qd * 4 + r] = vsum[mt][r];
    }
    __syncthreads();
    if (tid < 64) {
        Mpart[(size_t)pidx * 64 + tid] = mrow[tid];
        Lpart[(size_t)pidx * 64 + tid] = red_sum[0][tid] + red_sum[1][tid] +
                                         red_sum[2][tid] + red_sum[3][tid];
    }

    f32x4 acco[4];
#pragma unroll
    for (int mt = 0; mt < 4; mt++) acco[mt] = (f32x4){0.f, 0.f, 0.f, 0.f};
    const unsigned short* Vb = Vt + ((size_t)b * 512 + h * 64 + w * 16 + cc) * KVPAD + kv0;
#pragma unroll
    for (int ks = 0; ks < 8; ks++) {
        short8 vf = *(const short8*)&Vb[ks * 32 + qd * 8];
#pragma unroll
        for (int mt = 0; mt < 4; mt++) {
            short8 pf = *(const short8*)&P_lds[(size_t)(mt * 16 + cc) * 264 + ks * 32 + qd * 8];
            mfma16(acco[mt], pf, vf);
        }
    }
    float* Ob = Opart + (size_t)pidx * 4096;
#pragma unroll
    for (int mt = 0; mt < 4; mt++)
#pragma unroll
        for (int r = 0; r < 4; r++)
            Ob[(size_t)(mt * 16 + qd * 4 + r) * 64 + w * 16 + cc] = acco[mt][r];
}

// ---------------------------------------------------------------------------
// Combine split-kv partials over ACTIVE chunks only.
// ---------------------------------------------------------------------------
__global__ __launch_bounds__(256) void combine_kernel(
    const float* __restrict__ Opart, const float* __restrict__ Mpart,
    const float* __restrict__ Lpart, const int* __restrict__ cnt,
    unsigned short* __restrict__ AttnOut)
{
    __shared__ float wls[NCHUNK][16];
    __shared__ float invl[16];
    int bh = blockIdx.x >> 2, qg = blockIdx.x & 3;
    int b = bh >> 3, h = bh & 7;
    int pbase = bh * NCHUNK;
    int nact = (64 + cnt[b] + 255) >> 8;   // active chunks for this batch
    int tid = threadIdx.x;
    if (tid < 16) {
        int q = qg * 16 + tid;
        float M = -3.0e38f;
        for (int cn = 0; cn < nact; cn++)
            M = fmaxf(M, Mpart[(size_t)(pbase + cn) * 64 + q]);
        float l = 0.f;
        for (int cn = 0; cn < nact; cn++) {
            float wc = __expf(Mpart[(size_t)(pbase + cn) * 64 + q] - M);
            wls[cn][tid] = wc;
            l += wc * Lpart[(size_t)(pbase + cn) * 64 + q];
        }
        invl[tid] = 1.0f / l;
    }
    __syncthreads();
    int ql = tid >> 4, d4 = (tid & 15) * 4;
    int q = qg * 16 + ql;
    float ax = 0.f, ay = 0.f, az = 0.f, aw = 0.f;
    for (int cn = 0; cn < nact; cn++) {
        float wc = wls[cn][ql];
        float4 o = *(const float4*)&Opart[((size_t)(pbase + cn) * 64 + q) * 64 + d4];
        ax += wc * o.x; ay += wc * o.y; az += wc * o.z; aw += wc * o.w;
    }
    float iv = invl[ql];
    ushort4 pk;
    pk.x = f2bf(ax * iv); pk.y = f2bf(ay * iv);
    pk.z = f2bf(az * iv); pk.w = f2bf(aw * iv);
    *(ushort4*)&AttnOut[((size_t)b * 64 + q) * 512 + h * 64 + d4] = pk;
}

// ---------------------------------------------------------------------------
// Workspace layout (bytes). x_ln (0..134M) is dead after the big GEMM and is
// reused for attention partials / Qbuf / AttnOut.
// ---------------------------------------------------------------------------
#define OPART_OFF    ((size_t)0)            // 2112*64*64*4 = 34,603,008
#define MPART_OFF    ((size_t)34603008)     // 2112*64*4    =    540,672
#define LPART_OFF    ((size_t)35143680)
#define QBUF_OFF     ((size_t)35684352)     // 512*512*2    =    524,288
#define ATTNOUT_OFF  ((size_t)36208640)     // 512*512*2
#define XLN_OFF      ((size_t)0)            // 8*8192*1024*2 = 134,217,728
#define LATLN_OFF    ((size_t)134217728)    // 512*1024*2
#define KBUF_OFF     ((size_t)135266304)    // 8*8448*512*2 = 69,206,016
#define VT_OFF       ((size_t)204472320)    // 8*512*8448*2
#define WKVQT_OFF    ((size_t)273678336)    // 1536*1024*2 = 3,145,728
#define WOUTT_OFF    ((size_t)276824064)    // 1024*512*2  = 1,048,576
#define CNT_OFF      ((size_t)277872640)    // 8*4 ; end 277,872,672

extern "C" void kernel_launch(void* const* d_in, const int* in_sizes, int n_in,
                              void* d_out, int out_size, void* d_ws, size_t ws_size,
                              hipStream_t stream) {
    const float* x       = (const float*)d_in[0];
    const float* latents = (const float*)d_in[1];
    const int*   mask    = (const int*)d_in[2];
    const float* kv_gate = (const float*)d_in[3];
    const float* gm      = (const float*)d_in[4];
    const float* bm      = (const float*)d_in[5];
    const float* gl      = (const float*)d_in[6];
    const float* bl      = (const float*)d_in[7];
    const float* Wq      = (const float*)d_in[8];
    const float* Wk      = (const float*)d_in[9];
    const float* Wv      = (const float*)d_in[10];
    const float* Wout    = (const float*)d_in[11];
    float* out = (float*)d_out;

    char* ws = (char*)d_ws;
    float* Opart = (float*)(ws + OPART_OFF);
    float* Mpart = (float*)(ws + MPART_OFF);
    float* Lpart = (float*)(ws + LPART_OFF);
    unsigned short* Qbuf    = (unsigned short*)(ws + QBUF_OFF);
    unsigned short* AttnOut = (unsigned short*)(ws + ATTNOUT_OFF);
    unsigned short* x_ln    = (unsigned short*)(ws + XLN_OFF);
    unsigned short* lat_ln  = (unsigned short*)(ws + LATLN_OFF);
    unsigned short* Kbuf    = (unsigned short*)(ws + KBUF_OFF);
    unsigned short* Vt      = (unsigned short*)(ws + VT_OFF);
    unsigned short* WkvqT   = (unsigned short*)(ws + WKVQT_OFF);
    unsigned short* WoutT   = (unsigned short*)(ws + WOUTT_OFF);
    int* cnt = (int*)(ws + CNT_OFF);

    // 0) zero the per-batch slot counters (capture-legal async memset)
    hipMemsetAsync(cnt, 0, 8 * sizeof(int), stream);

    // 1) prep: LN (compacted x via atomic slots + latents) + weight transposes
    prep_kernel<<<17024, 256, 0, stream>>>(
        x, latents, mask, gm, bm, gl, bl, Wk, Wv, Wq, Wout,
        x_ln, lat_ln, WkvqT, WoutT, cnt);

    // 2) Big KV projection (compacted rows): -> K slots 64.., V^T slots 64..
    gemm_bf16<<<dim3(8, 512), 256, 0, stream>>>(
        x_ln, WkvqT, 1024, Kbuf, nullptr, Vt, nullptr,
        512, 1 << 30, 512, 8192, KVPAD, 64, 1.0f, 0.f, nullptr, cnt);

    // 3) Latent K/V/Q (K,V x kv_gate -> slots 0..63; Q x 0.125) in one GEMM
    gemm_bf16<<<dim3(12, 4), 256, 0, stream>>>(
        lat_ln, WkvqT, 1024, Kbuf, nullptr, Vt, Qbuf,
        512, 1024, 512, 64, KVPAD, 0, 1.0f, 0.125f, kv_gate, nullptr);

    // 4) Split-kv attention partials (inactive chunks exit immediately)
    attn_kernel<<<dim3(NCHUNK, 8, 8), 256, 0, stream>>>(
        Kbuf, Vt, Qbuf, cnt, Opart, Mpart, Lpart);

    // 5) Combine partials -> AttnOut bf16 [512][512]
    combine_kernel<<<256, 256, 0, stream>>>(Opart, Mpart, Lpart, cnt, AttnOut);

    // 6) Output projection: AttnOut(512x512) @ Wout -> out fp32 (8,64,1024)
    gemm_bf16<<<dim3(8, 4), 256, 0, stream>>>(
        AttnOut, WoutT, 512, nullptr, out, nullptr, nullptr,
        1 << 30, 1 << 30, 1024, 64, 64, 0, 1.0f, 0.f, nullptr, nullptr);
}

// Round 4
// 522.901 us; speedup vs baseline: 1.5964x; 1.5964x over previous
//
#include <hip/hip_runtime.h>
#include <stdint.h>

// ---------------------------------------------------------------------------
// PerceiverAttention fused pipeline (MI355X / gfx950), bf16 MFMA compute.
// b=8, f=8192, n=64, d=1024, heads=8, dim_head=64, inner=512.
// Round 4: atomic slot assignment (R3: 382us of same-line atomic serialization)
// replaced by a parallel 8-block prefix scan (~5us). Merged prep (LN + weight
// transposes) and fused latent K/V/Q GEMM retained from R3.
// ---------------------------------------------------------------------------

#define KVPAD 8448
#define NCHUNK 33

typedef __attribute__((ext_vector_type(8))) short short8;
typedef __attribute__((ext_vector_type(4))) float f32x4;

typedef __attribute__((address_space(1))) void gvoid;
typedef __attribute__((address_space(3))) void lvoid;

__device__ __forceinline__ unsigned short f2bf(float f) {
    union { float f; uint32_t u; } v; v.f = f;
    uint32_t u = v.u;
    u += 0x7fffu + ((u >> 16) & 1u);   // RNE
    return (unsigned short)(u >> 16);
}

__device__ __forceinline__ void mfma16(f32x4& c, short8 a, short8 b) {
    asm volatile("v_mfma_f32_16x16x32_bf16 %0, %1, %2, %0"
                 : "+v"(c) : "v"(a), "v"(b));
}

__device__ __forceinline__ void gl2lds16(const void* g, void* l) {
    __builtin_amdgcn_global_load_lds((gvoid*)g, (lvoid*)l, 16, 0, 0);
}

// ---------------------------------------------------------------------------
// Parallel prefix scan: one block per batch, 1024 threads; thread t owns rows
// f = k*1024 + t (k=0..7). Wave shfl-scan + 16-wave LDS scan. Contention-free.
// pfx[b][f] = compacted slot if row valid; cnt[b] = total valid.
// ---------------------------------------------------------------------------
__global__ __launch_bounds__(1024) void scan_kernel(
    const int* __restrict__ mask, int* __restrict__ pfx, int* __restrict__ cnt)
{
    __shared__ int wsum[16];
    int b = blockIdx.x;
    int t = threadIdx.x, lane = t & 63, w = t >> 6;
    int c[8], tot = 0;
#pragma unroll
    for (int k = 0; k < 8; k++) {
        c[k] = (mask[b * 8192 + k * 1024 + t] == 0) ? 1 : 0;
        tot += c[k];
    }
    int run = tot;                       // wave inclusive scan
#pragma unroll
    for (int off = 1; off < 64; off <<= 1) {
        int u = __shfl_up(run, off);
        if (lane >= off) run += u;
    }
    if (lane == 63) wsum[w] = run;
    __syncthreads();
    if (t < 16) {                        // scan the 16 wave totals (lanes 0..15)
        int v = wsum[t];
#pragma unroll
        for (int off = 1; off < 16; off <<= 1) {
            int u = __shfl_up(v, off);
            if (t >= off) v += u;
        }
        wsum[t] = v;                     // inclusive
        if (t == 15) cnt[b] = v;
    }
    __syncthreads();
    int base = (w ? wsum[w - 1] : 0) + (run - tot);  // exclusive prefix
#pragma unroll
    for (int k = 0; k < 8; k++) {
        pfx[b * 8192 + k * 1024 + t] = base;
        base += c[k];
    }
}

// ---------------------------------------------------------------------------
// prep: blocks [0,16512) = LayerNorm (x compacted via pfx + latents),
// blocks [16512,17024) = the 4 weight transposes (fp32 -> bf16, RxC -> CxR).
// ---------------------------------------------------------------------------
__global__ __launch_bounds__(256) void prep_kernel(
    const float* __restrict__ X, const float* __restrict__ latents,
    const int* __restrict__ mask, const int* __restrict__ pfx,
    const float* __restrict__ gm, const float* __restrict__ bm,
    const float* __restrict__ gl, const float* __restrict__ bl,
    const float* __restrict__ Wk, const float* __restrict__ Wv,
    const float* __restrict__ Wq, const float* __restrict__ Wout,
    unsigned short* __restrict__ x_ln, unsigned short* __restrict__ lat_ln,
    unsigned short* __restrict__ WkvqT, unsigned short* __restrict__ WoutT)
{
    __shared__ float t[64][65];
    int blk = blockIdx.x;
    if (blk >= 16512) {
        // ---- weight transpose part ----
        int tt = blk - 16512;              // 0..511
        int z = tt >> 7, u = tt & 127;
        const float* S; unsigned short* D; int R, C, bx, by;
        if (z == 0)      { S = Wk;   D = WkvqT;                       R = 1024; C = 512;  by = u >> 3; bx = u & 7; }
        else if (z == 1) { S = Wv;   D = WkvqT + (size_t)512 * 1024;  R = 1024; C = 512;  by = u >> 3; bx = u & 7; }
        else if (z == 2) { S = Wq;   D = WkvqT + (size_t)1024 * 1024; R = 1024; C = 512;  by = u >> 3; bx = u & 7; }
        else             { S = Wout; D = WoutT;                       R = 512;  C = 1024; by = u >> 4; bx = u & 15; }
        int r0 = by * 64, c0 = bx * 64;
#pragma unroll
        for (int i = 0; i < 16; i++) {
            int o = i * 256 + threadIdx.x;
            int rr = o >> 6, cc = o & 63;
            t[rr][cc] = S[(size_t)(r0 + rr) * C + c0 + cc];
        }
        __syncthreads();
#pragma unroll
        for (int i = 0; i < 16; i++) {
            int o = i * 256 + threadIdx.x;
            int cl = o >> 6, rl = o & 63;
            D[(size_t)(c0 + cl) * R + r0 + rl] = f2bf(t[rl][cl]);
        }
        return;
    }
    // ---- LayerNorm part: one wave per row ----
    int lane = threadIdx.x & 63;
    int row = blk * 4 + (threadIdx.x >> 6);
    const float *src, *g, *bet;
    unsigned short* dst;
    if (row < 65536) {
        if (mask[row] != 0) return;                 // padded: skip entirely
        int b = row >> 13;
        src = X + (size_t)row * 1024;
        dst = x_ln + ((size_t)b * 8192 + pfx[row]) * 1024;
        g = gm; bet = bm;
    } else {
        int r = row - 65536;                        // 0..511
        src = latents + (size_t)r * 1024;
        dst = lat_ln + (size_t)r * 1024;
        g = gl; bet = bl;
    }
    const float4* xr = (const float4*)src;
    float4 v[4];
    float s = 0.f, s2 = 0.f;
#pragma unroll
    for (int i = 0; i < 4; i++) {
        v[i] = xr[i * 64 + lane];
        s  += v[i].x + v[i].y + v[i].z + v[i].w;
        s2 += v[i].x*v[i].x + v[i].y*v[i].y + v[i].z*v[i].z + v[i].w*v[i].w;
    }
#pragma unroll
    for (int off = 1; off < 64; off <<= 1) {
        s += __shfl_xor(s, off);
        s2 += __shfl_xor(s2, off);
    }
    float mean = s * (1.0f / 1024.0f);
    float var  = s2 * (1.0f / 1024.0f) - mean * mean;
    float rs = rsqrtf(var + 1e-5f);
    ushort4* yr = (ushort4*)dst;
    const float4* gp = (const float4*)g;
    const float4* bp = (const float4*)bet;
#pragma unroll
    for (int i = 0; i < 4; i++) {
        int c4 = i * 64 + lane;
        float4 gg = gp[c4], bb = bp[c4];
        ushort4 o;
        o.x = f2bf((v[i].x - mean) * rs * gg.x + bb.x);
        o.y = f2bf((v[i].y - mean) * rs * gg.y + bb.y);
        o.z = f2bf((v[i].z - mean) * rs * gg.z + bb.z);
        o.w = f2bf((v[i].w - mean) * rs * gg.w + bb.w);
        yr[c4] = o;
    }
}

// ---------------------------------------------------------------------------
// Generic bf16 GEMM: C[M][N] = A[M][Kd] @ BT[N][Kd]^T, 128x128 tile, BK=64.
// m97 structure + 8x8 tile swizzle (for the 8x512 grid) + per-batch early
// exit on cnt. Store modes per output column:
//   col >= nq     : Q store,  Qb[(bq*64+rl+r)*512 + col-nq] * qscale (bf16)
//   col <  nsplit : row-major (bf16 Ck or fp32 Cf), row -> bq*Sstride+Ofs+rl
//   else          : transposed to CvT[(bq*512 + col-nsplit)*KVPAD + Ofs+rl]
// ---------------------------------------------------------------------------
__global__ __launch_bounds__(256) void gemm_bf16(
    const unsigned short* __restrict__ A, const unsigned short* __restrict__ BT,
    int Kd,
    unsigned short* __restrict__ Ck, float* __restrict__ Cf,
    unsigned short* __restrict__ CvT, unsigned short* __restrict__ Qb,
    int nsplit, int nq, int ldc, int P, int Sstride, int Ofs,
    float scale_const, float qscale, const float* __restrict__ scale_ptr,
    const int* __restrict__ cnt)
{
    __shared__ unsigned short a_lds[128 * 64];
    __shared__ unsigned short b_lds[128 * 64];
    int bx = blockIdx.x, by = blockIdx.y;
    if (gridDim.x == 8 && gridDim.y >= 8) {
        // 8x8 tile swizzle: 8 column-blocks sharing an A row-tile run in the
        // same 64-block window -> A re-reads hit L2/L3.
        int lid = by * 8 + bx;
        bx = lid & 7;
        by = (lid >> 6) * 8 + ((lid >> 3) & 7);
    }
    size_t rowbase = (size_t)by * 128;
    size_t colbase = (size_t)bx * 128;
    if (cnt) {  // compacted A: skip row-blocks past this batch's valid count
        int bq = (int)rowbase / P, rl = (int)rowbase - bq * P;
        if (rl >= cnt[bq]) return;
    }
    int tid = threadIdx.x;
    int lane = tid & 63;
    int wave = tid >> 6;
    int wrow = (wave >> 1) * 64, wcol = (wave & 1) * 64;
    int qd = lane >> 4, cc = lane & 15;

    f32x4 acc[4][4];
#pragma unroll
    for (int mt = 0; mt < 4; mt++)
#pragma unroll
        for (int nt = 0; nt < 4; nt++)
            acc[mt][nt] = (f32x4){0.f, 0.f, 0.f, 0.f};

    int kiters = Kd >> 6;
    for (int kt = 0; kt < kiters; kt++) {
        int k0 = kt << 6;
#pragma unroll
        for (int i = 0; i < 4; i++) {
            int s = i * 256 + tid;
            int m = s >> 3, kc = s & 7;
            int kg = kc ^ (m & 7);
            gl2lds16(A + (rowbase + m) * (size_t)Kd + (k0 + kg * 8), &a_lds[s * 8]);
        }
#pragma unroll
        for (int i = 0; i < 4; i++) {
            int s = i * 256 + tid;
            int m = s >> 3, kc = s & 7;
            int kg = kc ^ (m & 7);
            gl2lds16(BT + (colbase + m) * (size_t)Kd + (k0 + kg * 8), &b_lds[s * 8]);
        }
        __syncthreads();
#pragma unroll
        for (int ks = 0; ks < 2; ks++) {
            short8 af[4], bfr[4];
            int cg = ks * 4 + qd;
#pragma unroll
            for (int mt = 0; mt < 4; mt++) {
                int m = wrow + mt * 16 + cc;
                af[mt] = *(const short8*)&a_lds[(m * 8 + (cg ^ (m & 7))) * 8];
            }
#pragma unroll
            for (int nt = 0; nt < 4; nt++) {
                int n = wcol + nt * 16 + cc;
                bfr[nt] = *(const short8*)&b_lds[(n * 8 + (cg ^ (n & 7))) * 8];
            }
#pragma unroll
            for (int mt = 0; mt < 4; mt++)
#pragma unroll
                for (int nt = 0; nt < 4; nt++)
                    mfma16(acc[mt][nt], af[mt], bfr[nt]);
        }
        __syncthreads();
    }

    float sc = scale_const;
    if (scale_ptr) sc *= *scale_ptr;
#pragma unroll
    for (int mt = 0; mt < 4; mt++) {
        int g0 = (int)rowbase + wrow + mt * 16 + qd * 4;   // 4 consecutive rows
        int bq = g0 / P, rl = g0 - bq * P;
#pragma unroll
        for (int nt = 0; nt < 4; nt++) {
            int col = (int)colbase + wcol + nt * 16 + cc;
            if (col >= nq) {
#pragma unroll
                for (int r = 0; r < 4; r++)
                    Qb[(size_t)(bq * 64 + rl + r) * 512 + (col - nq)] =
                        f2bf(acc[mt][nt][r] * qscale);
            } else if (col < nsplit) {
                int idx0 = bq * Sstride + Ofs + rl;
                if (Cf) {
#pragma unroll
                    for (int r = 0; r < 4; r++)
                        Cf[(size_t)(idx0 + r) * ldc + col] = acc[mt][nt][r] * sc;
                } else {
#pragma unroll
                    for (int r = 0; r < 4; r++)
                        Ck[(size_t)(idx0 + r) * ldc + col] = f2bf(acc[mt][nt][r] * sc);
                }
            } else {
                ushort4 pk;
                pk.x = f2bf(acc[mt][nt][0] * sc);
                pk.y = f2bf(acc[mt][nt][1] * sc);
                pk.z = f2bf(acc[mt][nt][2] * sc);
                pk.w = f2bf(acc[mt][nt][3] * sc);
                *(ushort4*)&CvT[((size_t)bq * 512 + (col - nsplit)) * KVPAD + Ofs + rl] = pk;
            }
        }
    }
}

// ---------------------------------------------------------------------------
// Attention, split-kv over compacted layout. Grid (chunk=33, h=8, b=8).
// kv slots: [0..64) latents, [64..64+cnt[b]) features; len = 64+cnt[b].
// Blocks with kv0 >= len exit (their partials are never read by combine).
// ---------------------------------------------------------------------------
__global__ __launch_bounds__(256) void attn_kernel(
    const unsigned short* __restrict__ Kbuf,  // [8][8448][512]
    const unsigned short* __restrict__ Vt,    // [8][512][8448]
    const unsigned short* __restrict__ Qbuf,  // [8][64][512]
    const int* __restrict__ cnt,              // [8]
    float* __restrict__ Opart,                // [2112][64][64]
    float* __restrict__ Mpart,                // [2112][64]
    float* __restrict__ Lpart)                // [2112][64]
{
    __shared__ unsigned short P_lds[64 * 264];
    __shared__ float red_max[4][64];
    __shared__ float red_sum[4][64];
    __shared__ float mrow[64];

    int chunk = blockIdx.x, h = blockIdx.y, b = blockIdx.z;
    int len = 64 + cnt[b];
    int kv0 = chunk * 256;
    if (kv0 >= len) return;

    int tid = threadIdx.x, lane = tid & 63, w = tid >> 6;
    int qd = lane >> 4, cc = lane & 15;
    int pidx = (b * 8 + h) * NCHUNK + chunk;
    int kvw = kv0 + w * 64;

    short8 qf[4][2];
    const unsigned short* Qb = Qbuf + ((size_t)b * 64) * 512 + h * 64;
#pragma unroll
    for (int mt = 0; mt < 4; mt++)
#pragma unroll
        for (int ks = 0; ks < 2; ks++)
            qf[mt][ks] = *(const short8*)&Qb[(size_t)(mt * 16 + cc) * 512 + ks * 32 + qd * 8];

    f32x4 acc[4][4];
#pragma unroll
    for (int mt = 0; mt < 4; mt++)
#pragma unroll
        for (int nt = 0; nt < 4; nt++)
            acc[mt][nt] = (f32x4){0.f, 0.f, 0.f, 0.f};

    const unsigned short* Kb = Kbuf + (size_t)b * KVPAD * 512 + h * 64;
#pragma unroll
    for (int nt = 0; nt < 4; nt++) {
        int kvr = kvw + nt * 16 + cc;
#pragma unroll
        for (int ks = 0; ks < 2; ks++) {
            short8 kf = *(const short8*)&Kb[(size_t)kvr * 512 + ks * 32 + qd * 8];
#pragma unroll
            for (int mt = 0; mt < 4; mt++)
                mfma16(acc[mt][nt], qf[mt][ks], kf);
        }
    }
    // compacted: only slots >= len are invalid
#pragma unroll
    for (int nt = 0; nt < 4; nt++) {
        int kv = kvw + nt * 16 + cc;
        if (kv >= len) {
#pragma unroll
            for (int mt = 0; mt < 4; mt++)
#pragma unroll
                for (int r = 0; r < 4; r++) acc[mt][nt][r] = -1e30f;
        }
    }
    float vmax[4][4];
#pragma unroll
    for (int mt = 0; mt < 4; mt++)
#pragma unroll
        for (int r = 0; r < 4; r++)
            vmax[mt][r] = fmaxf(fmaxf(acc[mt][0][r], acc[mt][1][r]),
                                fmaxf(acc[mt][2][r], acc[mt][3][r]));
#pragma unroll
    for (int off = 1; off < 16; off <<= 1)
#pragma unroll
        for (int mt = 0; mt < 4; mt++)
#pragma unroll
            for (int r = 0; r < 4; r++)
                vmax[mt][r] = fmaxf(vmax[mt][r], __shfl_xor(vmax[mt][r], off));
    if (cc == 0) {
#pragma unroll
        for (int mt = 0; mt < 4; mt++)
#pragma unroll
            for (int r = 0; r < 4; r++)
                red_max[w][mt * 16 + qd * 4 + r] = vmax[mt][r];
    }
    __syncthreads();
    if (tid < 64)
        mrow[tid] = fmaxf(fmaxf(red_max[0][tid], red_max[1][tid]),
                          fmaxf(red_max[2][tid], red_max[3][tid]));
    __syncthreads();

    float vsum[4][4];
#pragma unroll
    for (int mt = 0; mt < 4; mt++)
#pragma unroll
        for (int r = 0; r < 4; r++) {
            int row = mt * 16 + qd * 4 + r;
            float m = mrow[row];
            float ssum = 0.f;
#pragma unroll
            for (int nt = 0; nt < 4; nt++) {
                float p = __expf(acc[mt][nt][r] - m);
                ssum += p;
                P_lds[row * 264 + w * 64 + nt * 16 + cc] = f2bf(p);
            }
            vsum[mt][r] = ssum;
        }
#pragma unroll
    for (int off = 1; off < 16; off <<= 1)
#pragma unroll
        for (int mt = 0; mt < 4; mt++)
#pragma unroll
            for (int r = 0; r < 4; r++)
                vsum[mt][r] += __shfl_xor(vsum[mt][r], off);
    if (cc == 0) {
#pragma unroll
        for (int mt = 0; mt < 4; mt++)
#pragma unroll
            for (int r = 0; r < 4; r++)
                red_sum[w][mt * 16 + qd * 4 + r] = vsum[mt][r];
    }
    __syncthreads();
    if (tid < 64) {
        Mpart[(size_t)pidx * 64 + tid] = mrow[tid];
        Lpart[(size_t)pidx * 64 + tid] = red_sum[0][tid] + red_sum[1][tid] +
                                         red_sum[2][tid] + red_sum[3][tid];
    }

    f32x4 acco[4];
#pragma unroll
    for (int mt = 0; mt < 4; mt++) acco[mt] = (f32x4){0.f, 0.f, 0.f, 0.f};
    const unsigned short* Vb = Vt + ((size_t)b * 512 + h * 64 + w * 16 + cc) * KVPAD + kv0;
#pragma unroll
    for (int ks = 0; ks < 8; ks++) {
        short8 vf = *(const short8*)&Vb[ks * 32 + qd * 8];
#pragma unroll
        for (int mt = 0; mt < 4; mt++) {
            short8 pf = *(const short8*)&P_lds[(size_t)(mt * 16 + cc) * 264 + ks * 32 + qd * 8];
            mfma16(acco[mt], pf, vf);
        }
    }
    float* Ob = Opart + (size_t)pidx * 4096;
#pragma unroll
    for (int mt = 0; mt < 4; mt++)
#pragma unroll
        for (int r = 0; r < 4; r++)
            Ob[(size_t)(mt * 16 + qd * 4 + r) * 64 + w * 16 + cc] = acco[mt][r];
}

// ---------------------------------------------------------------------------
// Combine split-kv partials over ACTIVE chunks only.
// ---------------------------------------------------------------------------
__global__ __launch_bounds__(256) void combine_kernel(
    const float* __restrict__ Opart, const float* __restrict__ Mpart,
    const float* __restrict__ Lpart, const int* __restrict__ cnt,
    unsigned short* __restrict__ AttnOut)
{
    __shared__ float wls[NCHUNK][16];
    __shared__ float invl[16];
    int bh = blockIdx.x >> 2, qg = blockIdx.x & 3;
    int b = bh >> 3, h = bh & 7;
    int pbase = bh * NCHUNK;
    int nact = (64 + cnt[b] + 255) >> 8;   // active chunks for this batch
    int tid = threadIdx.x;
    if (tid < 16) {
        int q = qg * 16 + tid;
        float M = -3.0e38f;
        for (int cn = 0; cn < nact; cn++)
            M = fmaxf(M, Mpart[(size_t)(pbase + cn) * 64 + q]);
        float l = 0.f;
        for (int cn = 0; cn < nact; cn++) {
            float wc = __expf(Mpart[(size_t)(pbase + cn) * 64 + q] - M);
            wls[cn][tid] = wc;
            l += wc * Lpart[(size_t)(pbase + cn) * 64 + q];
        }
        invl[tid] = 1.0f / l;
    }
    __syncthreads();
    int ql = tid >> 4, d4 = (tid & 15) * 4;
    int q = qg * 16 + ql;
    float ax = 0.f, ay = 0.f, az = 0.f, aw = 0.f;
    for (int cn = 0; cn < nact; cn++) {
        float wc = wls[cn][ql];
        float4 o = *(const float4*)&Opart[((size_t)(pbase + cn) * 64 + q) * 64 + d4];
        ax += wc * o.x; ay += wc * o.y; az += wc * o.z; aw += wc * o.w;
    }
    float iv = invl[ql];
    ushort4 pk;
    pk.x = f2bf(ax * iv); pk.y = f2bf(ay * iv);
    pk.z = f2bf(az * iv); pk.w = f2bf(aw * iv);
    *(ushort4*)&AttnOut[((size_t)b * 64 + q) * 512 + h * 64 + d4] = pk;
}

// ---------------------------------------------------------------------------
// Workspace layout (bytes). x_ln (0..134M) is dead after the big GEMM and is
// reused for attention partials / Qbuf / AttnOut.
// ---------------------------------------------------------------------------
#define OPART_OFF    ((size_t)0)            // 2112*64*64*4 = 34,603,008
#define MPART_OFF    ((size_t)34603008)     // 2112*64*4    =    540,672
#define LPART_OFF    ((size_t)35143680)
#define QBUF_OFF     ((size_t)35684352)     // 512*512*2    =    524,288
#define ATTNOUT_OFF  ((size_t)36208640)     // 512*512*2
#define XLN_OFF      ((size_t)0)            // 8*8192*1024*2 = 134,217,728
#define LATLN_OFF    ((size_t)134217728)    // 512*1024*2
#define KBUF_OFF     ((size_t)135266304)    // 8*8448*512*2 = 69,206,016
#define VT_OFF       ((size_t)204472320)    // 8*512*8448*2
#define WKVQT_OFF    ((size_t)273678336)    // 1536*1024*2 = 3,145,728
#define WOUTT_OFF    ((size_t)276824064)    // 1024*512*2  = 1,048,576
#define PFX_OFF      ((size_t)277872640)    // 8*8192*4 = 262,144
#define CNT_OFF      ((size_t)278134784)    // 8*4 ; end 278,134,816

extern "C" void kernel_launch(void* const* d_in, const int* in_sizes, int n_in,
                              void* d_out, int out_size, void* d_ws, size_t ws_size,
                              hipStream_t stream) {
    const float* x       = (const float*)d_in[0];
    const float* latents = (const float*)d_in[1];
    const int*   mask    = (const int*)d_in[2];
    const float* kv_gate = (const float*)d_in[3];
    const float* gm      = (const float*)d_in[4];
    const float* bm      = (const float*)d_in[5];
    const float* gl      = (const float*)d_in[6];
    const float* bl      = (const float*)d_in[7];
    const float* Wq      = (const float*)d_in[8];
    const float* Wk      = (const float*)d_in[9];
    const float* Wv      = (const float*)d_in[10];
    const float* Wout    = (const float*)d_in[11];
    float* out = (float*)d_out;

    char* ws = (char*)d_ws;
    float* Opart = (float*)(ws + OPART_OFF);
    float* Mpart = (float*)(ws + MPART_OFF);
    float* Lpart = (float*)(ws + LPART_OFF);
    unsigned short* Qbuf    = (unsigned short*)(ws + QBUF_OFF);
    unsigned short* AttnOut = (unsigned short*)(ws + ATTNOUT_OFF);
    unsigned short* x_ln    = (unsigned short*)(ws + XLN_OFF);
    unsigned short* lat_ln  = (unsigned short*)(ws + LATLN_OFF);
    unsigned short* Kbuf    = (unsigned short*)(ws + KBUF_OFF);
    unsigned short* Vt      = (unsigned short*)(ws + VT_OFF);
    unsigned short* WkvqT   = (unsigned short*)(ws + WKVQT_OFF);
    unsigned short* WoutT   = (unsigned short*)(ws + WOUTT_OFF);
    int* pfx = (int*)(ws + PFX_OFF);
    int* cnt = (int*)(ws + CNT_OFF);

    // 1) Parallel mask prefix scan (one block per batch, contention-free)
    scan_kernel<<<8, 1024, 0, stream>>>(mask, pfx, cnt);

    // 2) prep: LN (compacted x via pfx + latents) + weight transposes
    prep_kernel<<<17024, 256, 0, stream>>>(
        x, latents, mask, pfx, gm, bm, gl, bl, Wk, Wv, Wq, Wout,
        x_ln, lat_ln, WkvqT, WoutT);

    // 3) Big KV projection (compacted rows): -> K slots 64.., V^T slots 64..
    gemm_bf16<<<dim3(8, 512), 256, 0, stream>>>(
        x_ln, WkvqT, 1024, Kbuf, nullptr, Vt, nullptr,
        512, 1 << 30, 512, 8192, KVPAD, 64, 1.0f, 0.f, nullptr, cnt);

    // 4) Latent K/V/Q (K,V x kv_gate -> slots 0..63; Q x 0.125) in one GEMM
    gemm_bf16<<<dim3(12, 4), 256, 0, stream>>>(
        lat_ln, WkvqT, 1024, Kbuf, nullptr, Vt, Qbuf,
        512, 1024, 512, 64, KVPAD, 0, 1.0f, 0.125f, kv_gate, nullptr);

    // 5) Split-kv attention partials (inactive chunks exit immediately)
    attn_kernel<<<dim3(NCHUNK, 8, 8), 256, 0, stream>>>(
        Kbuf, Vt, Qbuf, cnt, Opart, Mpart, Lpart);

    // 6) Combine partials -> AttnOut bf16 [512][512]
    combine_kernel<<<256, 256, 0, stream>>>(Opart, Mpart, Lpart, cnt, AttnOut);

    // 7) Output projection: AttnOut(512x512) @ Wout -> out fp32 (8,64,1024)
    gemm_bf16<<<dim3(8, 4), 256, 0, stream>>>(
        AttnOut, WoutT, 512, nullptr, out, nullptr, nullptr,
        1 << 30, 1 << 30, 1024, 64, 64, 0, 1.0f, 0.f, nullptr, nullptr);
}